// Round 2
// baseline (621.043 us; speedup 1.0000x reference)
//
#include <hip/hip_runtime.h>

typedef float f4 __attribute__((ext_vector_type(4)));
typedef int   i4 __attribute__((ext_vector_type(4)));

static constexpr int D = 128;
static constexpr int NR_ATOM = 46, NR_DEG = 6, NR_CHG = 11, NR_HYB = 3,
                     NR_H = 5, NR_CHI = 4, NR_BOND = 5;

static constexpr int OFF_ATOM = 0;
static constexpr int OFF_DEG  = OFF_ATOM + NR_ATOM * D;   // 5888
static constexpr int OFF_CHG  = OFF_DEG  + NR_DEG  * D;   // 6656
static constexpr int OFF_HYB  = OFF_CHG  + NR_CHG  * D;   // 8064
static constexpr int OFF_H    = OFF_HYB  + NR_HYB  * D;   // 8448
static constexpr int OFF_CHI  = OFF_H    + NR_H    * D;   // 9088
static constexpr int OFF_BOND = OFF_CHI  + NR_CHI  * D;   // 9600
static constexpr int OFF_W    = OFF_BOND + NR_BOND * D;   // 10240
static constexpr int OFF_B    = OFF_W    + 7 * D;         // 11136
static constexpr int LDS_FLOATS = OFF_B + D;              // 11264 = 44 KiB

__global__ __launch_bounds__(512, 6)
void atom_featurizer_kernel(const int*   __restrict__ atom_idx,
                            const int*   __restrict__ degree_idx,
                            const int*   __restrict__ charge_idx,
                            const int*   __restrict__ hybrid_idx,
                            const int*   __restrict__ numh_idx,
                            const int*   __restrict__ chiral_idx,
                            const int*   __restrict__ bond_counts,  // [N,4]
                            const float* __restrict__ scalar3,      // [N,3]
                            const float* __restrict__ E_atom,
                            const float* __restrict__ E_deg,
                            const float* __restrict__ E_chg,
                            const float* __restrict__ E_hyb,
                            const float* __restrict__ E_h,
                            const float* __restrict__ E_chi,
                            const float* __restrict__ E_bond,
                            const float* __restrict__ W,            // [7,D]
                            const float* __restrict__ b,            // [D]
                            float*       __restrict__ out,          // [N,D]
                            int N)
{
    __shared__ float lds[LDS_FLOATS];
    const int tid = threadIdx.x;

    // ---- cooperative table staging (44 KiB, float4) ----
    {
        const float* srcs[9] = {E_atom, E_deg, E_chg, E_hyb, E_h, E_chi, E_bond, W, b};
        const int    offs[9] = {OFF_ATOM, OFF_DEG, OFF_CHG, OFF_HYB, OFF_H, OFF_CHI,
                                OFF_BOND, OFF_W, OFF_B};
        const int    cnts[9] = {NR_ATOM*D, NR_DEG*D, NR_CHG*D, NR_HYB*D, NR_H*D,
                                NR_CHI*D, NR_BOND*D, 7*D, D};
        for (int t = 0; t < 9; ++t) {
            const f4* s = (const f4*)srcs[t];
            f4* d = (f4*)(lds + offs[t]);
            const int n4 = cnts[t] >> 2;
            for (int i = tid; i < n4; i += 512) d[i] = s[i];
        }
    }
    __syncthreads();

    const int lane = tid & 31;             // element-group owner: floats 4*lane..4*lane+3
    const int grp  = tid >> 5;             // 16 groups per block
    const int d0   = lane << 2;
    const int groupsPerBlock = 512 >> 5;
    const int totalGroups = (int)gridDim.x * groupsPerBlock;

    auto ld = [&](int off) -> f4 { return *(const f4*)(lds + off + d0); };

    // hoist loop-invariant W rows + bias into registers (28+4 VGPRs)
    f4 w0 = ld(OFF_W + 0*D), w1 = ld(OFF_W + 1*D), w2 = ld(OFF_W + 2*D),
       w3 = ld(OFF_W + 3*D), w4 = ld(OFF_W + 4*D), w5 = ld(OFF_W + 5*D),
       w6 = ld(OFF_W + 6*D);
    f4 bias = ld(OFF_B);

    for (int n = (int)blockIdx.x * groupsPerBlock + grp; n < N; n += totalGroups) {
        const int ia  = atom_idx[n];
        const int ide = degree_idx[n];
        const int ic  = charge_idx[n];
        const int ih  = hybrid_idx[n];
        const int inh = numh_idx[n];
        const int ix  = chiral_idx[n];
        const i4  bc  = *(const i4*)(bond_counts + 4 * (size_t)n);
        const float s0 = scalar3[3 * (size_t)n + 0];
        const float s1 = scalar3[3 * (size_t)n + 1];
        const float s2 = scalar3[3 * (size_t)n + 2];

        // six categorical gathers
        f4 acc = ld(OFF_ATOM + ia * D);
        acc += ld(OFF_DEG + ide * D);
        acc += ld(OFF_CHG + ic  * D);
        acc += ld(OFF_HYB + ih  * D);
        acc += ld(OFF_H   + inh * D);
        acc += ld(OFF_CHI + ix  * D);

        // bond-context gathers, branchless mask
        const float m0 = bc.x > 0 ? 1.0f : 0.0f;
        const float m1 = bc.y > 0 ? 1.0f : 0.0f;
        const float m2 = bc.z > 0 ? 1.0f : 0.0f;
        const float m3 = bc.w > 0 ? 1.0f : 0.0f;
        acc += m0 * ld(OFF_BOND + bc.x * D);
        acc += m1 * ld(OFF_BOND + bc.y * D);
        acc += m2 * ld(OFF_BOND + bc.z * D);
        acc += m3 * ld(OFF_BOND + bc.w * D);

        // scal @ W + b   (scal = [s0,s1,s2, bc/4])
        acc += s0 * w0;
        acc += s1 * w1;
        acc += s2 * w2;
        acc += ((float)bc.x * 0.25f) * w3;
        acc += ((float)bc.y * 0.25f) * w4;
        acc += ((float)bc.z * 0.25f) * w5;
        acc += ((float)bc.w * 0.25f) * w6;
        acc += bias;

        __builtin_nontemporal_store(acc, (f4*)(out + (size_t)n * D + d0));
    }
}

extern "C" void kernel_launch(void* const* d_in, const int* in_sizes, int n_in,
                              void* d_out, int out_size, void* d_ws, size_t ws_size,
                              hipStream_t stream) {
    const int*   atom_idx    = (const int*)d_in[0];
    const int*   degree_idx  = (const int*)d_in[1];
    const int*   charge_idx  = (const int*)d_in[2];
    const int*   hybrid_idx  = (const int*)d_in[3];
    const int*   numh_idx    = (const int*)d_in[4];
    const int*   chiral_idx  = (const int*)d_in[5];
    const int*   bond_counts = (const int*)d_in[6];
    const float* scalar3     = (const float*)d_in[7];
    const float* E_atom      = (const float*)d_in[8];
    const float* E_deg       = (const float*)d_in[9];
    const float* E_chg       = (const float*)d_in[10];
    const float* E_hyb       = (const float*)d_in[11];
    const float* E_h         = (const float*)d_in[12];
    const float* E_chi       = (const float*)d_in[13];
    const float* E_bond      = (const float*)d_in[14];
    const float* W           = (const float*)d_in[15];
    const float* b           = (const float*)d_in[16];
    float*       out         = (float*)d_out;
    const int N = in_sizes[0];

    // 768 blocks = 3 blocks/CU (LDS-capped), grid-stride over atoms.
    atom_featurizer_kernel<<<768, 512, 0, stream>>>(
        atom_idx, degree_idx, charge_idx, hybrid_idx, numh_idx, chiral_idx,
        bond_counts, scalar3, E_atom, E_deg, E_chg, E_hyb, E_h, E_chi, E_bond,
        W, b, out, N);
}